// Round 4
// baseline (277.338 us; speedup 1.0000x reference)
//
#include <hip/hip_runtime.h>

#define NCLS  32
#define SOS   30
#define EOS   31
#define LOG2E 1.4426950408889634f
#define LN2   0.6931471805599453f

typedef __attribute__((ext_vector_type(8))) short short8;
typedef __attribute__((ext_vector_type(4))) float f32x4;

__device__ __forceinline__ uint32_t rne_bf16(float x) {
    uint32_t u = __float_as_uint(x);
    return (u + 0x7fffu + ((u >> 16) & 1u)) >> 16;
}

// MFMA-based CRF forward, linear (exp) domain.
//
// One wave per 16 batches (block=64, grid=B/16=128). Per step t:
//   D[class c, batch n] = sum_k ET[c,k] * E[k,n]    (2x mfma 16x16x32 bf16)
//   E_new[c,n] = ef_t[c,n] * D[c,n],  ef = 2^(feat*log2e + mT[c] - 6) (prefetched,
//   OFF the critical chain — no transcendentals in the serial chain at all)
//   mask in {0,1} -> select.  Renorm every 4 steps by exponent of E[class0]
//   (bpermute, exact power-of-2 scale; accumulated into per-batch C).
//
// Layouts (gfx950 mfma_f32_16x16x32_bf16):
//   A (static = ET):  A[m=lane&15][k=(lane>>4)*8+j]     [verified, m120]
//   B (dynamic = E):  B[k=(lane>>4)*8+j][n=lane&15]     [standard duality]
//   C/D:              D[row=(lane>>4)*4+reg][col=lane&15] [verified, m89]
// So lane(q,n0) produces classes {4q+r, 16+4q+r} of batch n0 and must supply
// classes {8q..8q+7} of batch n0 next step: a 4-lane transpose done via one
// ds_write_b128 + two ds_read_b64 in a pair-interleaved, quad-swizzled LDS row.
__global__ __launch_bounds__(64, 1) void crf_fwd(const float* __restrict__ feats,
                                                 const float* __restrict__ mask,
                                                 const float* __restrict__ trans,
                                                 float* __restrict__ out,
                                                 int S, int B) {
    __shared__ __align__(16) uint32_t ebuf[16 * 20];   // 16 batch rows, stride 20 dwords
    __shared__ float mts[32];

    const int lane = threadIdx.x;      // block = 64 = one wave
    const int q   = lane >> 4;
    const int n0  = lane & 15;
    const int q4  = q * 4;
    const int b   = blockIdx.x * 16 + n0;
    const int bb  = (b < B) ? b : (B - 1);

    // ---- static A fragments: A1 = ET rows 0..15 (m=n0), A2 = rows 16..31 ----
    const float* t1 = trans + n0 * NCLS + q * 8;
    const float* t2 = trans + (16 + n0) * NCLS + q * 8;
    float th1[8], th2[8];
    float mx1 = -3.4e38f, mx2 = -3.4e38f;
    #pragma unroll
    for (int j = 0; j < 8; ++j) {
        th1[j] = t1[j] * LOG2E; mx1 = fmaxf(mx1, th1[j]);
        th2[j] = t2[j] * LOG2E; mx2 = fmaxf(mx2, th2[j]);
    }
    mx1 = fmaxf(mx1, __shfl_xor(mx1, 16, 64));
    mx1 = fmaxf(mx1, __shfl_xor(mx1, 32, 64));
    mx2 = fmaxf(mx2, __shfl_xor(mx2, 16, 64));
    mx2 = fmaxf(mx2, __shfl_xor(mx2, 32, 64));
    union { uint32_t u[4]; short8 s; } a1u, a2u;
    #pragma unroll
    for (int j2 = 0; j2 < 4; ++j2) {
        a1u.u[j2] = rne_bf16(__builtin_amdgcn_exp2f(th1[2*j2]   - mx1))
                  | (rne_bf16(__builtin_amdgcn_exp2f(th1[2*j2+1] - mx1)) << 16);
        a2u.u[j2] = rne_bf16(__builtin_amdgcn_exp2f(th2[2*j2]   - mx2))
                  | (rne_bf16(__builtin_amdgcn_exp2f(th2[2*j2+1] - mx2)) << 16);
    }
    const short8 a1 = a1u.s, a2 = a2u.s;

    // distribute per-class row-max to D-layout classes via LDS (one-time)
    mts[n0] = mx1; mts[16 + n0] = mx2;          // 4 lanes write identical values
    __builtin_amdgcn_wave_barrier();
    const float mtd1x = mts[q4 + 0] - 6.0f, mtd1y = mts[q4 + 1] - 6.0f;
    const float mtd1z = mts[q4 + 2] - 6.0f, mtd1w = mts[q4 + 3] - 6.0f;
    const float mtd2x = mts[16 + q4 + 0] - 6.0f, mtd2y = mts[16 + q4 + 1] - 6.0f;
    const float mtd2z = mts[16 + q4 + 2] - 6.0f, mtd2w = mts[16 + q4 + 3] - 6.0f;

    // epilogue factors 2^(That[EOS][c]) for this lane's 8 classes
    const float eosA0 = __builtin_amdgcn_exp2f(trans[EOS * NCLS + q4 + 0] * LOG2E);
    const float eosA1 = __builtin_amdgcn_exp2f(trans[EOS * NCLS + q4 + 1] * LOG2E);
    const float eosA2 = __builtin_amdgcn_exp2f(trans[EOS * NCLS + q4 + 2] * LOG2E);
    const float eosA3 = __builtin_amdgcn_exp2f(trans[EOS * NCLS + q4 + 3] * LOG2E);
    const float eosB0 = __builtin_amdgcn_exp2f(trans[EOS * NCLS + 16 + q4 + 0] * LOG2E);
    const float eosB1 = __builtin_amdgcn_exp2f(trans[EOS * NCLS + 16 + q4 + 1] * LOG2E);
    const float eosB2 = __builtin_amdgcn_exp2f(trans[EOS * NCLS + 16 + q4 + 2] * LOG2E);
    const float eosB3 = __builtin_amdgcn_exp2f(trans[EOS * NCLS + 16 + q4 + 3] * LOG2E);

    // LDS addresses (lane-constant, quad-swizzled to spread banks)
    uint32_t* wp = &ebuf[n0 * 20 + (((q + n0) & 3) << 2)];
    const int base1 = ((q & 1) << 3) | ((q >> 1) << 1);      // {0,8,2,10}
    const int sw0 = n0 * 20 + (((((base1)     >> 2) + n0) & 3) << 2) + (base1 & 3);
    const int sw1 = n0 * 20 + (((((base1 + 4) >> 2) + n0) & 3) << 2) + (base1 & 3);
    const uint2* rp0 = (const uint2*)&ebuf[sw0];
    const uint2* rp1 = (const uint2*)&ebuf[sw1];

    // ---- E init: linear alpha0 = 2^alpha0 : SOS -> 1, others -> 0 ----
    float E1x = 0.f, E1y = 0.f, E1z = 0.f, E1w = 0.f;                  // classes q4+r
    float E2x = 0.f, E2y = 0.f, E2z = 0.f, E2w = 0.f;                  // classes 16+q4+r
    if (16 + q4 + 0 == SOS) E2x = 1.f;
    if (16 + q4 + 1 == SOS) E2y = 1.f;
    if (16 + q4 + 2 == SOS) E2z = 1.f;
    if (16 + q4 + 3 == SOS) E2w = 1.f;
    float C = 0.0f;

    const size_t fstep = (size_t)B * NCLS;

#define LOADSLOT(Rf1, Rf2, Rm, T) {                                          \
        const float* _p = feats + (size_t)(T) * fstep + (size_t)bb * NCLS;   \
        Rf1 = *(const float4*)(_p + q4);                                     \
        Rf2 = *(const float4*)(_p + 16 + q4);                                \
        Rm  = mask[(size_t)(T) * B + bb];                                    \
    }

#define CONV(Rf1, Rf2, Rm, Ea, Eb, Md) {                                     \
        Ea.x = __builtin_amdgcn_exp2f(fmaf(Rf1.x, LOG2E, mtd1x));            \
        Ea.y = __builtin_amdgcn_exp2f(fmaf(Rf1.y, LOG2E, mtd1y));            \
        Ea.z = __builtin_amdgcn_exp2f(fmaf(Rf1.z, LOG2E, mtd1z));            \
        Ea.w = __builtin_amdgcn_exp2f(fmaf(Rf1.w, LOG2E, mtd1w));            \
        Eb.x = __builtin_amdgcn_exp2f(fmaf(Rf2.x, LOG2E, mtd2x));            \
        Eb.y = __builtin_amdgcn_exp2f(fmaf(Rf2.y, LOG2E, mtd2y));            \
        Eb.z = __builtin_amdgcn_exp2f(fmaf(Rf2.z, LOG2E, mtd2z));            \
        Eb.w = __builtin_amdgcn_exp2f(fmaf(Rf2.w, LOG2E, mtd2w));            \
        Md = Rm;                                                             \
    }

#define STEPCHAIN(EFa, EFb, EM, RENORM) {                                    \
        uint32_t p0 = __builtin_amdgcn_perm(__float_as_uint(E1y), __float_as_uint(E1x), 0x07060302u); \
        uint32_t p1 = __builtin_amdgcn_perm(__float_as_uint(E1w), __float_as_uint(E1z), 0x07060302u); \
        uint32_t p2 = __builtin_amdgcn_perm(__float_as_uint(E2y), __float_as_uint(E2x), 0x07060302u); \
        uint32_t p3 = __builtin_amdgcn_perm(__float_as_uint(E2w), __float_as_uint(E2z), 0x07060302u); \
        *(uint4*)wp = make_uint4(p0, p1, p2, p3);                            \
        __builtin_amdgcn_wave_barrier();                                     \
        uint2 _lo = *rp0; uint2 _hi = *rp1;                                  \
        union { uint32_t u[4]; short8 s; } _bu;                              \
        _bu.u[0] = _lo.x; _bu.u[1] = _lo.y; _bu.u[2] = _hi.x; _bu.u[3] = _hi.y; \
        f32x4 _z = {0.f, 0.f, 0.f, 0.f};                                     \
        f32x4 _d1 = __builtin_amdgcn_mfma_f32_16x16x32_bf16(a1, _bu.s, _z, 0, 0, 0); \
        f32x4 _d2 = __builtin_amdgcn_mfma_f32_16x16x32_bf16(a2, _bu.s, _z, 0, 0, 0); \
        bool _sel = (EM != 0.0f);                                            \
        E1x = _sel ? _d1[0] * EFa.x : E1x;  E1y = _sel ? _d1[1] * EFa.y : E1y; \
        E1z = _sel ? _d1[2] * EFa.z : E1z;  E1w = _sel ? _d1[3] * EFa.w : E1w; \
        E2x = _sel ? _d2[0] * EFb.x : E2x;  E2y = _sel ? _d2[1] * EFb.y : E2y; \
        E2z = _sel ? _d2[2] * EFb.z : E2z;  E2w = _sel ? _d2[3] * EFb.w : E2w; \
        if (RENORM) {                                                        \
            float _Dv = __shfl(E1x, n0, 64);                                 \
            uint32_t _eb = (__float_as_uint(_Dv) >> 23) & 0xffu;             \
            C += (float)((int)_eb - 127);                                    \
            float _sc = __uint_as_float((254u - _eb) << 23);                 \
            E1x *= _sc; E1y *= _sc; E1z *= _sc; E1w *= _sc;                  \
            E2x *= _sc; E2y *= _sc; E2z *= _sc; E2w *= _sc;                  \
        }                                                                    \
    }

    // ---- prefetch rings: raw depth 4, ef depth 2 ----
    float4 r1_0, r1_1, r1_2, r1_3, r2_0, r2_1, r2_2, r2_3;
    float  rm_0, rm_1, rm_2, rm_3;
    float4 e1_0, e1_1, e2_0, e2_1;
    float  m_0, m_1;

    const int Sm1 = S - 1;
    LOADSLOT(r1_0, r2_0, rm_0, (0 < S ? 0 : Sm1));
    LOADSLOT(r1_1, r2_1, rm_1, (1 < S ? 1 : Sm1));
    LOADSLOT(r1_2, r2_2, rm_2, (2 < S ? 2 : Sm1));
    LOADSLOT(r1_3, r2_3, rm_3, (3 < S ? 3 : Sm1));
    CONV(r1_0, r2_0, rm_0, e1_0, e2_0, m_0);
    CONV(r1_1, r2_1, rm_1, e1_1, e2_1, m_1);

    int tb = 0;
    for (; tb + 4 <= S; tb += 4) {
        int t4 = tb + 4; t4 = t4 < Sm1 ? t4 : Sm1;
        int t5 = tb + 5; t5 = t5 < Sm1 ? t5 : Sm1;
        int t6 = tb + 6; t6 = t6 < Sm1 ? t6 : Sm1;
        int t7 = tb + 7; t7 = t7 < Sm1 ? t7 : Sm1;
        // u=0: consume ef0(t), conv raw2(t+2)->ef0, load raw0<-t+4
        STEPCHAIN(e1_0, e2_0, m_0, false);
        CONV(r1_2, r2_2, rm_2, e1_0, e2_0, m_0);
        LOADSLOT(r1_0, r2_0, rm_0, t4);
        // u=1
        STEPCHAIN(e1_1, e2_1, m_1, false);
        CONV(r1_3, r2_3, rm_3, e1_1, e2_1, m_1);
        LOADSLOT(r1_1, r2_1, rm_1, t5);
        // u=2
        STEPCHAIN(e1_0, e2_0, m_0, false);
        CONV(r1_0, r2_0, rm_0, e1_0, e2_0, m_0);
        LOADSLOT(r1_2, r2_2, rm_2, t6);
        // u=3 (renorm)
        STEPCHAIN(e1_1, e2_1, m_1, true);
        CONV(r1_1, r2_1, rm_1, e1_1, e2_1, m_1);
        LOADSLOT(r1_3, r2_3, rm_3, t7);
    }
    // tail (S % 4 != 0): direct loads, inline conversion
    for (int t = tb; t < S; ++t) {
        float4 tf1, tf2; float tmv;
        LOADSLOT(tf1, tf2, tmv, t);
        float4 te1, te2; float tem;
        CONV(tf1, tf2, tmv, te1, te2, tem);
        STEPCHAIN(te1, te2, tem, false);
    }

    // ---- epilogue: out[b] = ln2 * (C + 6S + log2( sum_c E[c] * 2^That[EOS][c] )) ----
    float w = E1x * eosA0 + E1y * eosA1 + E1z * eosA2 + E1w * eosA3
            + E2x * eosB0 + E2y * eosB1 + E2z * eosB2 + E2w * eosB3;
    w += __shfl_xor(w, 16, 64);
    w += __shfl_xor(w, 32, 64);
    if (q == 0 && b < B) {
        out[b] = LN2 * (C + 6.0f * (float)S + __builtin_amdgcn_logf(w));
    }
#undef LOADSLOT
#undef CONV
#undef STEPCHAIN
}

extern "C" void kernel_launch(void* const* d_in, const int* in_sizes, int n_in,
                              void* d_out, int out_size, void* d_ws, size_t ws_size,
                              hipStream_t stream) {
    const float* feats = (const float*)d_in[0];
    const float* mask  = (const float*)d_in[1];
    const float* trans = (const float*)d_in[2];
    float* out = (float*)d_out;

    const int B = out_size;            // batch  (2048)
    const int S = in_sizes[1] / B;     // seq_len (512)

    dim3 block(64);                    // one wave
    dim3 grid((B + 15) / 16);          // 16 batches per wave
    hipLaunchKernelGGL(crf_fwd, grid, block, 0, stream, feats, mask, trans, out, S, B);
}